// Round 1
// baseline (264.741 us; speedup 1.0000x reference)
//
#include <hip/hip_runtime.h>

// BatchedCauchyKernel3d: out[b,i,j] = 1 / (1 + d/sqrt(scx[b,i]*scy[b,j]))
// d = clip(|x_i|^2 + |y_j|^2 - 2 x_i.y_j, 1e-10, 1e6)
// scx = clip(sample_x . clip(scale,1e-6,1e6), 1e-10, 1e6); likewise scy.
// Note 1/(1+d/s) == s/(s+d): one rcp, one sqrt per element.

constexpr int kB  = 4;
constexpr int kNX = 4096;
constexpr int kNY = 4096;
constexpr int kF  = 16;

// ---------------- pre-pass: per-point (|p|^2, clipped scale-dot) ------------
__global__ __launch_bounds__(256) void row_stats_kernel(
    const float* __restrict__ x, const float* __restrict__ y,
    const float* __restrict__ sx, const float* __restrict__ sy,
    const float* __restrict__ scale,
    float2* __restrict__ rx, float2* __restrict__ ry, int nper)
{
    int t = blockIdx.x * blockDim.x + threadIdx.x;
    if (t >= 2 * nper) return;
    const float* pts; const float* smp; float2* dst; int idx;
    if (t < nper) { pts = x; smp = sx; dst = rx; idx = t; }
    else          { pts = y; smp = sy; dst = ry; idx = t - nper; }

    const float* p = pts + (size_t)idx * 3;
    float sq = p[0] * p[0] + p[1] * p[1] + p[2] * p[2];

    const float4* s4 = (const float4*)(smp + (size_t)idx * kF);
    const float4* c4 = (const float4*)scale;
    float acc = 0.f;
#pragma unroll
    for (int k = 0; k < kF / 4; ++k) {
        float4 sv = s4[k];
        float4 cv = c4[k];
        acc += sv.x * fminf(fmaxf(cv.x, 1e-6f), 1e6f);
        acc += sv.y * fminf(fmaxf(cv.y, 1e-6f), 1e6f);
        acc += sv.z * fminf(fmaxf(cv.z, 1e-6f), 1e6f);
        acc += sv.w * fminf(fmaxf(cv.w, 1e-6f), 1e6f);
    }
    float sc = fminf(fmaxf(acc, 1e-10f), 1e6f);
    dst[idx] = make_float2(sq, sc);
}

// ---------------- main: 4 rows x 4 cols per thread --------------------------
// thread t -> jc = t & 1023 (j0 = 4*jc), rowtile = t >> 10 (i0 = 4*(rowtile&1023),
// b = rowtile >> 10). Stores 4x float4, fully coalesced along j.
__device__ __forceinline__ void cauchy_tile(
    int b, int i0, int j0,
    const float* __restrict__ x, const float* __restrict__ y,
    const float sqx[4], const float scx[4],
    const float sqy[4], const float scy[4],
    const float xxx[4], const float xyy[4], const float xzz[4],
    const float yxx[4], const float yyy[4], const float yzz[4],
    float* __restrict__ out)
{
    size_t obase = ((size_t)b * kNX + i0) * (size_t)kNY + j0;
#pragma unroll
    for (int r = 0; r < 4; ++r) {
        float4 o;
        float* op = (float*)&o;
#pragma unroll
        for (int k = 0; k < 4; ++k) {
            float dot = xxx[r] * yxx[k] + xyy[r] * yyy[k] + xzz[r] * yzz[k];
            float d = fmaf(-2.f, dot, sqx[r] + sqy[k]);
            d = fminf(fmaxf(d, 1e-10f), 1e6f);
            float pr = fminf(fmaxf(scx[r] * scy[k], 1e-10f), 1e12f);
            float s = __builtin_amdgcn_sqrtf(pr);
            op[k] = s * __builtin_amdgcn_rcpf(s + d);
        }
        *(float4*)(out + obase + (size_t)r * kNY) = o;
    }
}

__global__ __launch_bounds__(256) void cauchy_main_kernel(
    const float* __restrict__ x, const float* __restrict__ y,
    const float2* __restrict__ rx, const float2* __restrict__ ry,
    float* __restrict__ out)
{
    const int t = blockIdx.x * 256 + threadIdx.x;
    const int jc = t & (kNY / 4 - 1);
    const int rowtile = t >> 10;
    const int b  = rowtile >> 10;
    const int i0 = (rowtile & (kNX / 4 - 1)) * 4;
    const int j0 = jc * 4;

    // y side: 4 points = 12 contiguous floats (16B aligned), + 4 float2 stats
    const float4* yv = (const float4*)(y + ((size_t)b * kNY + j0) * 3);
    float4 ya = yv[0], yb = yv[1], yc = yv[2];
    const float4* ryv = (const float4*)(ry + (size_t)b * kNY + j0);
    float4 r01 = ryv[0], r23 = ryv[1];

    // x side: 4 rows = 12 contiguous floats (broadcast within 1024 threads)
    const float4* xv = (const float4*)(x + ((size_t)b * kNX + i0) * 3);
    float4 xa = xv[0], xb = xv[1], xc = xv[2];
    const float4* rxv = (const float4*)(rx + (size_t)b * kNX + i0);
    float4 q01 = rxv[0], q23 = rxv[1];

    const float yxx[4] = {ya.x, ya.w, yb.z, yc.y};
    const float yyy[4] = {ya.y, yb.x, yb.w, yc.z};
    const float yzz[4] = {ya.z, yb.y, yc.x, yc.w};
    const float sqy[4] = {r01.x, r01.z, r23.x, r23.z};
    const float scy[4] = {r01.y, r01.w, r23.y, r23.w};

    const float xxx[4] = {xa.x, xa.w, xb.z, xc.y};
    const float xyy[4] = {xa.y, xb.x, xb.w, xc.z};
    const float xzz[4] = {xa.z, xb.y, xc.x, xc.w};
    const float sqx[4] = {q01.x, q01.z, q23.x, q23.z};
    const float scx[4] = {q01.y, q01.w, q23.y, q23.w};

    cauchy_tile(b, i0, j0, x, y, sqx, scx, sqy, scy,
                xxx, xyy, xzz, yxx, yyy, yzz, out);
}

// ---------------- fallback (ws too small): stats inline ---------------------
__global__ __launch_bounds__(256) void cauchy_fallback_kernel(
    const float* __restrict__ x, const float* __restrict__ y,
    const float* __restrict__ sx, const float* __restrict__ sy,
    const float* __restrict__ scale, float* __restrict__ out)
{
    const int t = blockIdx.x * 256 + threadIdx.x;
    const int jc = t & (kNY / 4 - 1);
    const int rowtile = t >> 10;
    const int b  = rowtile >> 10;
    const int i0 = (rowtile & (kNX / 4 - 1)) * 4;
    const int j0 = jc * 4;

    float4 c[4];
    const float4* c4 = (const float4*)scale;
#pragma unroll
    for (int k = 0; k < 4; ++k) {
        float4 cv = c4[k];
        c[k].x = fminf(fmaxf(cv.x, 1e-6f), 1e6f);
        c[k].y = fminf(fmaxf(cv.y, 1e-6f), 1e6f);
        c[k].z = fminf(fmaxf(cv.z, 1e-6f), 1e6f);
        c[k].w = fminf(fmaxf(cv.w, 1e-6f), 1e6f);
    }

    const float4* yv = (const float4*)(y + ((size_t)b * kNY + j0) * 3);
    float4 ya = yv[0], yb = yv[1], yc = yv[2];
    const float4* xv = (const float4*)(x + ((size_t)b * kNX + i0) * 3);
    float4 xa = xv[0], xb = xv[1], xc = xv[2];

    const float yxx[4] = {ya.x, ya.w, yb.z, yc.y};
    const float yyy[4] = {ya.y, yb.x, yb.w, yc.z};
    const float yzz[4] = {ya.z, yb.y, yc.x, yc.w};
    const float xxx[4] = {xa.x, xa.w, xb.z, xc.y};
    const float xyy[4] = {xa.y, xb.x, xb.w, xc.z};
    const float xzz[4] = {xa.z, xb.y, xc.x, xc.w};

    float sqx[4], scx[4], sqy[4], scy[4];
#pragma unroll
    for (int r = 0; r < 4; ++r) {
        sqx[r] = xxx[r] * xxx[r] + xyy[r] * xyy[r] + xzz[r] * xzz[r];
        sqy[r] = yxx[r] * yxx[r] + yyy[r] * yyy[r] + yzz[r] * yzz[r];
        const float4* a4 = (const float4*)(sx + ((size_t)b * kNX + i0 + r) * kF);
        const float4* b4 = (const float4*)(sy + ((size_t)b * kNY + j0 + r) * kF);
        float accx = 0.f, accy = 0.f;
#pragma unroll
        for (int k = 0; k < 4; ++k) {
            float4 av = a4[k], bv = b4[k], cv = c[k];
            accx += av.x * cv.x + av.y * cv.y + av.z * cv.z + av.w * cv.w;
            accy += bv.x * cv.x + bv.y * cv.y + bv.z * cv.z + bv.w * cv.w;
        }
        scx[r] = fminf(fmaxf(accx, 1e-10f), 1e6f);
        scy[r] = fminf(fmaxf(accy, 1e-10f), 1e6f);
    }

    cauchy_tile(b, i0, j0, x, y, sqx, scx, sqy, scy,
                xxx, xyy, xzz, yxx, yyy, yzz, out);
}

extern "C" void kernel_launch(void* const* d_in, const int* in_sizes, int n_in,
                              void* d_out, int out_size, void* d_ws, size_t ws_size,
                              hipStream_t stream) {
    const float* x     = (const float*)d_in[0];
    const float* y     = (const float*)d_in[1];
    const float* sx    = (const float*)d_in[2];
    const float* sy    = (const float*)d_in[3];
    const float* scale = (const float*)d_in[4];
    float* out = (float*)d_out;

    const int nper = kB * kNX;                       // 16384 points per side
    const size_t need = (size_t)2 * nper * sizeof(float2);  // 256 KiB
    const int main_blocks = (kB * kNX * kNY / 16) / 256;    // 16384

    if (ws_size >= need) {
        float2* rx = (float2*)d_ws;
        float2* ry = rx + nper;
        row_stats_kernel<<<(2 * nper + 255) / 256, 256, 0, stream>>>(
            x, y, sx, sy, scale, rx, ry, nper);
        cauchy_main_kernel<<<main_blocks, 256, 0, stream>>>(x, y, rx, ry, out);
    } else {
        cauchy_fallback_kernel<<<main_blocks, 256, 0, stream>>>(
            x, y, sx, sy, scale, out);
    }
}